// Round 15
// baseline (3528.309 us; speedup 1.0000x reference)
//
#include <hip/hip_runtime.h>
#include <hip/hip_bf16.h>

// ============================================================================
// SimpleGatedUnit. R15 = R14 (4 batch domains x 32 col-blocks, data-poll
// sentinel exchange, frag-major layout, LDS-transpose publish, 4-way split
// chains, early publish) + STREAMED PARTIAL CONSUME:
// poll is split into issue/wait with two register banks (FA/FB). Per attempt:
// wait bank -> per-fragment freshness mask (frag kb <-> producers 2kb,2kb+1)
// -> if incomplete, re-issue other bank -> MFMA fresh fragments WHILE refill
// is in flight. Straggler wait now overlaps useful work; tight-arrival case
// costs only ~16 ballots vs R14.
// ============================================================================

typedef __attribute__((ext_vector_type(4))) float  f32x4;
typedef __attribute__((ext_vector_type(4))) float  floatx4;
typedef __attribute__((ext_vector_type(8))) short  short8;
typedef __attribute__((ext_vector_type(4))) short  short4v;
typedef __attribute__((ext_vector_type(2))) int    int2v;

#define NSTEP  511
#define NGRP   4
#define NCOLB  32
#define NAN_S  ((short)0x7FFF)

#define OFF_HB0  4096
#define OFF_HB1  (OFF_HB0 + 65536)
#define OFF_GB0  (OFF_HB1 + 65536)
#define OFF_GB1  (OFF_GB0 + 65536)
#define OFF_HF32 (OFF_GB1 + 65536)
#define OFF_UPK  (OFF_HF32 + 131072)
#define OFF_WT   (OFF_UPK + 1572864)
#define OFF_XX   (OFF_WT + 1572864)
#define PER_T_BYTES (3u * 64u * 512u * 2u)

__device__ __forceinline__ float b2f(short s) {
  unsigned u = ((unsigned)(unsigned short)s) << 16;
  return __builtin_bit_cast(float, u);
}
__device__ __forceinline__ short f2b(float f) {
  unsigned u = __builtin_bit_cast(unsigned, f);
  u += 0x7fffu + ((u >> 16) & 1u);
  return (short)(u >> 16);
}
__device__ __forceinline__ float hsig(float x) {
  return fminf(fmaxf(0.2f * x + 0.5f, 0.0f), 1.0f);
}
__device__ __forceinline__ float softplus_f(float x) {
  return fmaxf(x, 0.0f) + log1pf(expf(-fabsf(x)));
}

__device__ __forceinline__ void st8_cp(short* p, int2v v) {
  asm volatile("global_store_dwordx2 %0, %1, off sc0 sc1"
               :: "v"(p), "v"(v) : "memory");
}

struct Frags {
  short8 f0,f1,f2,f3,f4,f5,f6,f7,f8,f9,f10,f11,f12,f13,f14,f15;
};

// issue 16 x 16B IC loads, NO wait (values usable only after vmw())
__device__ __forceinline__ void ld_issue16(const short* p0, const short* p1,
                                           const short* p2, const short* p3,
                                           Frags& F) {
  asm volatile(
    "global_load_dwordx4 %0,  %16, off sc0 sc1\n\t"
    "global_load_dwordx4 %1,  %16, off offset:1024 sc0 sc1\n\t"
    "global_load_dwordx4 %2,  %16, off offset:2048 sc0 sc1\n\t"
    "global_load_dwordx4 %3,  %16, off offset:3072 sc0 sc1\n\t"
    "global_load_dwordx4 %4,  %17, off sc0 sc1\n\t"
    "global_load_dwordx4 %5,  %17, off offset:1024 sc0 sc1\n\t"
    "global_load_dwordx4 %6,  %17, off offset:2048 sc0 sc1\n\t"
    "global_load_dwordx4 %7,  %17, off offset:3072 sc0 sc1\n\t"
    "global_load_dwordx4 %8,  %18, off sc0 sc1\n\t"
    "global_load_dwordx4 %9,  %18, off offset:1024 sc0 sc1\n\t"
    "global_load_dwordx4 %10, %18, off offset:2048 sc0 sc1\n\t"
    "global_load_dwordx4 %11, %18, off offset:3072 sc0 sc1\n\t"
    "global_load_dwordx4 %12, %19, off sc0 sc1\n\t"
    "global_load_dwordx4 %13, %19, off offset:1024 sc0 sc1\n\t"
    "global_load_dwordx4 %14, %19, off offset:2048 sc0 sc1\n\t"
    "global_load_dwordx4 %15, %19, off offset:3072 sc0 sc1"
    : "=&v"(F.f0), "=&v"(F.f1), "=&v"(F.f2), "=&v"(F.f3),
      "=&v"(F.f4), "=&v"(F.f5), "=&v"(F.f6), "=&v"(F.f7),
      "=&v"(F.f8), "=&v"(F.f9), "=&v"(F.f10), "=&v"(F.f11),
      "=&v"(F.f12), "=&v"(F.f13), "=&v"(F.f14), "=&v"(F.f15)
    : "v"(p0), "v"(p1), "v"(p2), "v"(p3)
    : "memory");
}

// wait for all outstanding vmem; binds the bank's regs so no use precedes it
__device__ __forceinline__ void vmw(Frags& F) {
  asm volatile("s_waitcnt vmcnt(0)"
    : "+v"(F.f0), "+v"(F.f1), "+v"(F.f2), "+v"(F.f3),
      "+v"(F.f4), "+v"(F.f5), "+v"(F.f6), "+v"(F.f7),
      "+v"(F.f8), "+v"(F.f9), "+v"(F.f10), "+v"(F.f11),
      "+v"(F.f12), "+v"(F.f13), "+v"(F.f14), "+v"(F.f15)
    :: "memory");
}

#define FRESHBIT(F, i) \
  (((unsigned)__all(((F).f##i[0] != NAN_S) & ((F).f##i[4] != NAN_S))) << i)

__device__ __forceinline__ unsigned freshmask_impl(const Frags& F) {
  unsigned m = 0;
  m |= FRESHBIT(F, 0);  m |= FRESHBIT(F, 1);  m |= FRESHBIT(F, 2);
  m |= FRESHBIT(F, 3);  m |= FRESHBIT(F, 4);  m |= FRESHBIT(F, 5);
  m |= FRESHBIT(F, 6);  m |= FRESHBIT(F, 7);  m |= FRESHBIT(F, 8);
  m |= FRESHBIT(F, 9);  m |= FRESHBIT(F, 10); m |= FRESHBIT(F, 11);
  m |= FRESHBIT(F, 12); m |= FRESHBIT(F, 13); m |= FRESHBIT(F, 14);
  m |= FRESHBIT(F, 15);
  return m;
}

#define MF(a, b, c) __builtin_amdgcn_mfma_f32_16x16x32_bf16(a, b, c, 0, 0, 0)

// stage-1 consume: dual MFMA (U into au, U_in into ai) for fresh frags
#define CONS1_ONE(F, i) \
  if ((fr >> i) & 1) { \
    short8 b0 = *((const short8*)Ub + ((0 * 16 + i) * 64 + lane)); \
    short8 b1 = *((const short8*)Ub + ((1 * 16 + i) * 64 + lane)); \
    au[i & 3] = MF((F).f##i, b0, au[i & 3]); \
    ai[i & 3] = MF((F).f##i, b1, ai[i & 3]); \
  }
#define CONS1_ALL(F) do { \
  CONS1_ONE(F, 0)  CONS1_ONE(F, 1)  CONS1_ONE(F, 2)  CONS1_ONE(F, 3)  \
  CONS1_ONE(F, 4)  CONS1_ONE(F, 5)  CONS1_ONE(F, 6)  CONS1_ONE(F, 7)  \
  CONS1_ONE(F, 8)  CONS1_ONE(F, 9)  CONS1_ONE(F, 10) CONS1_ONE(F, 11) \
  CONS1_ONE(F, 12) CONS1_ONE(F, 13) CONS1_ONE(F, 14) CONS1_ONE(F, 15) \
} while (0)

// stage-2 consume: single MFMA (U_out into ao)
#define CONS2_ONE(F, i) \
  if ((fr >> i) & 1) { \
    short8 b2 = *((const short8*)Ub + ((2 * 16 + i) * 64 + lane)); \
    ao[i & 3] = MF((F).f##i, b2, ao[i & 3]); \
  }
#define CONS2_ALL(F) do { \
  CONS2_ONE(F, 0)  CONS2_ONE(F, 1)  CONS2_ONE(F, 2)  CONS2_ONE(F, 3)  \
  CONS2_ONE(F, 4)  CONS2_ONE(F, 5)  CONS2_ONE(F, 6)  CONS2_ONE(F, 7)  \
  CONS2_ONE(F, 8)  CONS2_ONE(F, 9)  CONS2_ONE(F, 10) CONS2_ONE(F, 11) \
  CONS2_ONE(F, 12) CONS2_ONE(F, 13) CONS2_ONE(F, 14) CONS2_ONE(F, 15) \
} while (0)

// ---------------------------------------------------------------------------
__global__ __launch_bounds__(256) void prep_kernel(
    const float* __restrict__ U0, const float* __restrict__ U1, const float* __restrict__ U2,
    const float* __restrict__ W0, const float* __restrict__ W1, const float* __restrict__ W2,
    short* __restrict__ Upk, short* __restrict__ Wt)
{
  int e = blockIdx.x * 256 + threadIdx.x;
  if (e < 786432) {
    int mat = e >> 18;
    int rem = e & 262143;
    int c   = rem >> 13;
    int r2  = rem & 8191;
    int kb  = r2 >> 9;
    int r3  = r2 & 511;
    int l = r3 >> 3, j = r3 & 7;
    int k = kb * 32 + ((l >> 4) << 3) + j;
    int d = c * 16 + (l & 15);
    const float* U = (mat == 0) ? U0 : (mat == 1 ? U1 : U2);
    Upk[e] = f2b(U[k * 512 + d]);
  } else if (e < 1572864) {
    int e2 = e - 786432;
    int mat = e2 >> 18;
    int rem = e2 & 262143;
    int n = rem >> 9, k = rem & 511;
    const float* W = (mat == 0) ? W0 : (mat == 1 ? W1 : W2);
    Wt[e2] = f2b(W[k * 512 + n]);
  }
}

__global__ __launch_bounds__(256) void init_kernel(
    short* hb0, short* hb1, short* gb0, short* gb1, float* h_f32)
{
  int e = blockIdx.x * 256 + threadIdx.x;
  if (e < 32768) {
    hb0[e] = NAN_S; hb1[e] = 0;
    gb0[e] = NAN_S; gb1[e] = NAN_S;
    h_f32[e] = 0.0f;
  }
}

__global__ __launch_bounds__(256) void gemm_xw(
    const float* __restrict__ X, const short* __restrict__ Wt,
    const float* __restrict__ bias0, const float* __restrict__ bias1,
    const float* __restrict__ bias2, short* __restrict__ out,
    int base_row, int cnt_rows)
{
  __shared__ __align__(16) short Al[128][48];
  __shared__ __align__(16) short Bl[128][48];
  const int bm = blockIdx.x, bn = blockIdx.y, mat = blockIdx.z;
  const short* Wm = Wt + (size_t)mat * (512 * 512);
  const float* bias = (mat == 0) ? bias0 : (mat == 1 ? bias1 : bias2);
  short* om = out + (size_t)mat * ((size_t)cnt_rows * 512);
  const int tid = threadIdx.x, lane = tid & 63, wid = tid >> 6;
  const int wm = wid >> 1, wn = wid & 1;
  const int m0 = bm * 128, n0g = bn * 128;
  f32x4 acc[4][4];
  #pragma unroll
  for (int i = 0; i < 4; ++i)
    #pragma unroll
    for (int j = 0; j < 4; ++j) acc[i][j] = (f32x4){0.f, 0.f, 0.f, 0.f};

  for (int k0 = 0; k0 < 512; k0 += 32) {
    #pragma unroll
    for (int i = 0; i < 4; ++i) {
      int q = tid + 256 * i;
      int r = q >> 3, seg = q & 7;
      int ml = m0 + r;
      short4v h4 = {0, 0, 0, 0};
      if (ml < cnt_rows) {
        int gl = base_row + ml;
        int t = gl >> 6, bb = gl & 63;
        floatx4 v = *(const floatx4*)(X + ((size_t)bb * 512 + t) * 512 + k0 + seg * 4);
        h4 = (short4v){ f2b(v[0]), f2b(v[1]), f2b(v[2]), f2b(v[3]) };
      }
      *(short4v*)&Al[r][seg * 4] = h4;
    }
    #pragma unroll
    for (int i = 0; i < 2; ++i) {
      int q = tid + 256 * i;
      int r = q >> 2, seg = q & 3;
      *(short8*)&Bl[r][seg * 8] = *(const short8*)(Wm + (size_t)(n0g + r) * 512 + k0 + seg * 8);
    }
    __syncthreads();
    const int ko = (lane >> 4) * 8;
    short8 af[4], bf4[4];
    #pragma unroll
    for (int mt = 0; mt < 4; ++mt)
      af[mt] = *(const short8*)&Al[wm * 64 + mt * 16 + (lane & 15)][ko];
    #pragma unroll
    for (int nt = 0; nt < 4; ++nt)
      bf4[nt] = *(const short8*)&Bl[wn * 64 + nt * 16 + (lane & 15)][ko];
    #pragma unroll
    for (int mt = 0; mt < 4; ++mt)
      #pragma unroll
      for (int nt = 0; nt < 4; ++nt)
        acc[mt][nt] = __builtin_amdgcn_mfma_f32_16x16x32_bf16(af[mt], bf4[nt], acc[mt][nt], 0, 0, 0);
    __syncthreads();
  }
  const int rq = lane >> 4, cq = lane & 15;
  #pragma unroll
  for (int mt = 0; mt < 4; ++mt) {
    #pragma unroll
    for (int nt = 0; nt < 4; ++nt) {
      int n = n0g + wn * 64 + nt * 16 + cq;
      float bv = bias[n];
      #pragma unroll
      for (int rr = 0; rr < 4; ++rr) {
        int m = m0 + wm * 64 + mt * 16 + rq * 4 + rr;
        if (m < cnt_rows) om[(size_t)m * 512 + n] = f2b(acc[mt][nt][rr] + bv);
      }
    }
  }
}

// ---------------------------------------------------------------------------
// scan segment: 128 blocks x 64 threads; domain g = blk>>5, col-owner c=blk&31.
// ---------------------------------------------------------------------------
__global__ __launch_bounds__(64, 1) void scan_kernel(
    short* hb0, short* hb1, short* gb0, short* gb1, float* h_f32,
    const short* __restrict__ Upk,
    const short* __restrict__ xx,
    const float* __restrict__ bu_in, const float* __restrict__ bu_out,
    float* __restrict__ out,
    int s0, int nsteps, int nt)
{
  __shared__ __align__(16) short Ub[3][16][64][8];
  __shared__ __align__(16) short St[256];
  const int lane = threadIdx.x & 63;
  const int g = blockIdx.x >> 5;
  const int c = blockIdx.x & 31;
  {
    const size_t cs = (size_t)c * 8192;
    short8* dst = (short8*)Ub;
    for (int i = lane; i < 3072; i += 64) {
      int mat = i >> 10;
      int rem = i & 1023;
      dst[i] = *(const short8*)(Upk + (size_t)mat * 262144 + cs + (size_t)rem * 8);
    }
  }
  const int colg = c * 16 + (lane & 15);
  const float binr  = bu_in[colg];
  const float boutr = bu_out[colg];
  const size_t XSZ = (size_t)nt * 64 * 512;
  const int gbase = g * 8192;
  const int fofs = gbase + ((lane >> 4) << 7) + ((lane & 15) << 3);
  const int pofs = gbase + ((c >> 1) << 9) + ((c & 1) << 8) + (lane << 2);
  const int sw = ((lane & 15) >> 3) * 128 + ((lane >> 4) << 5) + (lane & 7);
  short* hbuf[2] = { hb0, hb1 };
  short* gbuf[2] = { gb0, gb1 };
  const int2v NANPAIR = { 0x7FFF7FFF, 0x7FFF7FFF };

  float hown[4];
  #pragma unroll
  for (int r = 0; r < 4; ++r)
    hown[r] = h_f32[(size_t)(g * 16 + (lane >> 4) * 4 + r) * 512 + colg];
  __syncthreads();

  Frags FA, FB;

  for (int s = 0; s < nsteps; ++s) {
    const int sg = s0 + s;
    const int p = sg & 1;
    // hoisted xx loads for BOTH stages (cached)
    float a1[4], a0[4], p1[4], p0[4], q1[4], q0[4];
    #pragma unroll
    for (int r = 0; r < 4; ++r) {
      int gr = g * 16 + (lane >> 4) * 4 + r;
      size_t i1 = ((size_t)(s + 1) * 64 + gr) * 512 + colg;
      size_t i0 = ((size_t)s * 64 + gr) * 512 + colg;
      a1[r] = b2f(xx[i1]);           a0[r] = b2f(xx[i0]);
      p1[r] = b2f(xx[XSZ + i1]);     p0[r] = b2f(xx[XSZ + i0]);
      q1[r] = b2f(xx[2 * XSZ + i1]); q0[r] = b2f(xx[2 * XSZ + i0]);
    }

    // ---- stage 1: streamed consume of h(sg-1); dual MFMA; publish g ----
    const short* hbp = hbuf[p ^ 1] + fofs;
    f32x4 au[4], ai[4];
    au[0] = au[1] = au[2] = au[3] = (f32x4){0.f, 0.f, 0.f, 0.f};
    ai[0] = ai[1] = ai[2] = ai[3] = (f32x4){0.f, 0.f, 0.f, 0.f};
    {
      unsigned done = 0; int guard = 0;
      ld_issue16(hbp, hbp + 2048, hbp + 4096, hbp + 6144, FA);
      for (;;) {
        vmw(FA);
        unsigned fr = freshmask_impl(FA) & ~done;
        unsigned nd = done | fr;
        if (nd != 0xFFFFu) ld_issue16(hbp, hbp + 2048, hbp + 4096, hbp + 6144, FB);
        CONS1_ALL(FA);
        done = nd;
        if (done == 0xFFFFu) break;
        if (++guard > 4096) break;
        vmw(FB);
        fr = freshmask_impl(FB) & ~done;
        nd = done | fr;
        if (nd != 0xFFFFu) ld_issue16(hbp, hbp + 2048, hbp + 4096, hbp + 6144, FA);
        CONS1_ALL(FB);
        done = nd;
        if (done == 0xFFFFu) break;
        if (++guard > 4096) break;
      }
    }
    // consume complete => all col-blocks' g(sg-1) consumed => reset slice
    if (sg > 0) st8_cp(gbuf[p ^ 1] + pofs, NANPAIR);
    f32x4 accin = (ai[0] + ai[1]) + (ai[2] + ai[3]);
    #pragma unroll
    for (int r = 0; r < 4; ++r) {
      float zin = hsig(p1[r] + accin[r] + p0[r] + binr);
      St[sw + r * 8] = f2b(zin * hown[r]);
    }
    st8_cp(gbuf[p] + pofs, *(const int2v*)&St[lane << 2]);  // publish g early
    f32x4 accu = (au[0] + au[1]) + (au[2] + au[3]);
    float zr[4];
    #pragma unroll
    for (int r = 0; r < 4; ++r)
      zr[r] = hsig(a1[r] + accu[r] + a0[r]);

    // ---- stage 2: streamed consume of g(sg); publish h ----
    const short* gbp = gbuf[p] + fofs;
    f32x4 ao[4];
    ao[0] = ao[1] = ao[2] = ao[3] = (f32x4){0.f, 0.f, 0.f, 0.f};
    {
      unsigned done = 0; int guard = 0;
      ld_issue16(gbp, gbp + 2048, gbp + 4096, gbp + 6144, FA);
      for (;;) {
        vmw(FA);
        unsigned fr = freshmask_impl(FA) & ~done;
        unsigned nd = done | fr;
        if (nd != 0xFFFFu) ld_issue16(gbp, gbp + 2048, gbp + 4096, gbp + 6144, FB);
        CONS2_ALL(FA);
        done = nd;
        if (done == 0xFFFFu) break;
        if (++guard > 4096) break;
        vmw(FB);
        fr = freshmask_impl(FB) & ~done;
        nd = done | fr;
        if (nd != 0xFFFFu) ld_issue16(gbp, gbp + 2048, gbp + 4096, gbp + 6144, FA);
        CONS2_ALL(FB);
        done = nd;
        if (done == 0xFFFFu) break;
        if (++guard > 4096) break;
      }
    }
    st8_cp(hbuf[p ^ 1] + pofs, NANPAIR);   // all consumed h(sg-1) => reset
    f32x4 acco = (ao[0] + ao[1]) + (ao[2] + ao[3]);
    #pragma unroll
    for (int r = 0; r < 4; ++r) {
      float pre = q1[r] + acco[r] + q0[r] + boutr;
      float zo = softplus_f(pre);
      float hn = (1.0f - zr[r]) * hown[r] + zr[r] * zo;
      hown[r] = hn;
      St[sw + r * 8] = f2b(hn);
    }
    st8_cp(hbuf[p] + pofs, *(const int2v*)&St[lane << 2]);  // publish h early
    if (sg == NSTEP - 1) {
      #pragma unroll
      for (int r = 0; r < 4; ++r) {
        int gr = g * 16 + (lane >> 4) * 4 + r;
        out[(size_t)gr * 512 + colg] = hown[r];
      }
    }
  }
  #pragma unroll
  for (int r = 0; r < 4; ++r)
    h_f32[(size_t)(g * 16 + (lane >> 4) * 4 + r) * 512 + colg] = hown[r];
  asm volatile("s_waitcnt vmcnt(0)" ::: "memory");
}

extern "C" void kernel_launch(void* const* d_in, const int* in_sizes, int n_in,
                              void* d_out, int out_size, void* d_ws, size_t ws_size,
                              hipStream_t stream)
{
  const float* X      = (const float*)d_in[0];
  const float* W      = (const float*)d_in[1];
  const float* b      = (const float*)d_in[2];
  const float* W_in   = (const float*)d_in[3];
  const float* b_in   = (const float*)d_in[4];
  const float* W_out  = (const float*)d_in[5];
  const float* b_out  = (const float*)d_in[6];
  const float* U      = (const float*)d_in[7];
  const float* U_in   = (const float*)d_in[8];
  const float* U_out  = (const float*)d_in[9];
  const float* bu_in  = (const float*)d_in[10];
  const float* bu_out = (const float*)d_in[11];
  float* out = (float*)d_out;
  char* ws = (char*)d_ws;
  short* hb0  = (short*)(ws + OFF_HB0);
  short* hb1  = (short*)(ws + OFF_HB1);
  short* gb0  = (short*)(ws + OFF_GB0);
  short* gb1  = (short*)(ws + OFF_GB1);
  float* h_f32= (float*)(ws + OFF_HF32);
  short* Upk  = (short*)(ws + OFF_UPK);
  short* Wt   = (short*)(ws + OFF_WT);
  short* xx   = (short*)(ws + OFF_XX);

  size_t avail = (ws_size > (size_t)OFF_XX) ? ws_size - (size_t)OFF_XX : 0;
  int max_t = (int)(avail / PER_T_BYTES);
  if (max_t > 512) max_t = 512;
  int SEG = max_t - 1;
  if (SEG < 1) SEG = 1;

  prep_kernel<<<6144, 256, 0, stream>>>(U, U_in, U_out, W, W_in, W_out, Upk, Wt);
  init_kernel<<<128, 256, 0, stream>>>(hb0, hb1, gb0, gb1, h_f32);

  int s0 = 0;
  while (s0 < NSTEP) {
    int nsteps = NSTEP - s0; if (nsteps > SEG) nsteps = SEG;
    int nt = nsteps + 1;
    int rows = nt * 64;
    int gx = (rows + 127) / 128;
    gemm_xw<<<dim3(gx, 4, 3), 256, 0, stream>>>(X, Wt, b, b_in, b_out, xx,
                                                s0 * 64, rows);
    scan_kernel<<<NGRP * NCOLB, 64, 0, stream>>>(hb0, hb1, gb0, gb1, h_f32,
                                                 Upk, xx, bu_in, bu_out, out,
                                                 s0, nsteps, nt);
    s0 += nsteps;
  }
}

// Round 16
// 2675.112 us; speedup vs baseline: 1.3189x; 1.3189x over previous
//
#include <hip/hip_runtime.h>
#include <hip/hip_bf16.h>

// ============================================================================
// SimpleGatedUnit. R16 = R14 exact revert (verified best: 2638us total).
// R15's streamed-partial-consume regressed (+35%: eager double-bank reissues
// inflated IC traffic; ballots+divergent consume cost on every round) and is
// abandoned. Design: 4 batch domains x 32 col-blocks, 1 wave each; data-poll
// sentinel exchange (bf16-NaN 0x7FFF); frag-major layout (contiguous 1KB
// frag runs); one-asm-block 16-load consume; LDS-transpose 8B publish;
// 4-way split MFMA accumulator chains; early publish. ~2.4us/round = IC
// visibility+detect+read floor (3 protocol families converged within 15%).
// ============================================================================

typedef __attribute__((ext_vector_type(4))) float  f32x4;
typedef __attribute__((ext_vector_type(4))) float  floatx4;
typedef __attribute__((ext_vector_type(8))) short  short8;
typedef __attribute__((ext_vector_type(4))) short  short4v;
typedef __attribute__((ext_vector_type(2))) int    int2v;

#define NSTEP  511
#define NGRP   4           // independent batch domains (16 rows each)
#define NCOLB  32          // column blocks per domain (16 cols each)
#define NAN_S  ((short)0x7FFF)

// ws layout (bytes)
#define OFF_HB0  4096                     // h bf16 frag-major, parity 0 (64 KB: 4 grp x 16 KB)
#define OFF_HB1  (OFF_HB0 + 65536)        // h parity 1
#define OFF_GB0  (OFF_HB1 + 65536)        // g parity 0
#define OFF_GB1  (OFF_GB0 + 65536)        // g parity 1
#define OFF_HF32 (OFF_GB1 + 65536)        // h fp32 [64][512] row-major (128 KB)
#define OFF_UPK  (OFF_HF32 + 131072)      // packed U,U_in,U_out bf16  (1.5 MB)
#define OFF_WT   (OFF_UPK + 1572864)      // W^T bf16 [3][512 n][512 k](1.5 MB)
#define OFF_XX   (OFF_WT + 1572864)       // xx,x_in,x_out bf16 segment buffer
#define PER_T_BYTES (3u * 64u * 512u * 2u)  // xx bytes per time row (196608)

__device__ __forceinline__ float b2f(short s) {
  unsigned u = ((unsigned)(unsigned short)s) << 16;
  return __builtin_bit_cast(float, u);
}
__device__ __forceinline__ short f2b(float f) {  // RNE fp32->bf16
  unsigned u = __builtin_bit_cast(unsigned, f);
  u += 0x7fffu + ((u >> 16) & 1u);
  return (short)(u >> 16);
}
__device__ __forceinline__ float hsig(float x) {
  return fminf(fmaxf(0.2f * x + 0.5f, 0.0f), 1.0f);
}
__device__ __forceinline__ float softplus_f(float x) {
  return fmaxf(x, 0.0f) + log1pf(expf(-fabsf(x)));
}

// 8B store to the agent coherence point (IC)
__device__ __forceinline__ void st8_cp(short* p, int2v v) {
  asm volatile("global_store_dwordx2 %0, %1, off sc0 sc1"
               :: "v"(p), "v"(v) : "memory");
}

// 16 x 16B fragment loads from IC in ONE asm block. Frag-major (per group):
// per-kb stride 1024B; 4 bases cover kb {0-3,4-7,8-11,12-15}.
__device__ __forceinline__ void ld_frags16(const short* p0, const short* p1,
                                           const short* p2, const short* p3,
                                           short8 f[16]) {
  short8 f0,f1,f2,f3,f4,f5,f6,f7,f8,f9,f10,f11,f12,f13,f14,f15;
  asm volatile(
    "global_load_dwordx4 %0,  %16, off sc0 sc1\n\t"
    "global_load_dwordx4 %1,  %16, off offset:1024 sc0 sc1\n\t"
    "global_load_dwordx4 %2,  %16, off offset:2048 sc0 sc1\n\t"
    "global_load_dwordx4 %3,  %16, off offset:3072 sc0 sc1\n\t"
    "global_load_dwordx4 %4,  %17, off sc0 sc1\n\t"
    "global_load_dwordx4 %5,  %17, off offset:1024 sc0 sc1\n\t"
    "global_load_dwordx4 %6,  %17, off offset:2048 sc0 sc1\n\t"
    "global_load_dwordx4 %7,  %17, off offset:3072 sc0 sc1\n\t"
    "global_load_dwordx4 %8,  %18, off sc0 sc1\n\t"
    "global_load_dwordx4 %9,  %18, off offset:1024 sc0 sc1\n\t"
    "global_load_dwordx4 %10, %18, off offset:2048 sc0 sc1\n\t"
    "global_load_dwordx4 %11, %18, off offset:3072 sc0 sc1\n\t"
    "global_load_dwordx4 %12, %19, off sc0 sc1\n\t"
    "global_load_dwordx4 %13, %19, off offset:1024 sc0 sc1\n\t"
    "global_load_dwordx4 %14, %19, off offset:2048 sc0 sc1\n\t"
    "global_load_dwordx4 %15, %19, off offset:3072 sc0 sc1\n\t"
    "s_waitcnt vmcnt(0)"
    : "=&v"(f0), "=&v"(f1), "=&v"(f2), "=&v"(f3),
      "=&v"(f4), "=&v"(f5), "=&v"(f6), "=&v"(f7),
      "=&v"(f8), "=&v"(f9), "=&v"(f10), "=&v"(f11),
      "=&v"(f12), "=&v"(f13), "=&v"(f14), "=&v"(f15)
    : "v"(p0), "v"(p1), "v"(p2), "v"(p3)
    : "memory");
  f[0]=f0; f[1]=f1; f[2]=f2; f[3]=f3; f[4]=f4; f[5]=f5; f[6]=f6; f[7]=f7;
  f[8]=f8; f[9]=f9; f[10]=f10; f[11]=f11; f[12]=f12; f[13]=f13; f[14]=f14; f[15]=f15;
}

// poll-load: retry until no lane sees the sentinel in either 8B half
__device__ __forceinline__ void poll_frags16(const short* base, short8 f[16]) {
  const short* q0 = base;
  const short* q1 = base + 2048;
  const short* q2 = base + 4096;
  const short* q3 = base + 6144;
  int guard = 0;
  for (;;) {
    ld_frags16(q0, q1, q2, q3, f);
    int fresh = 1;
    #pragma unroll
    for (int i = 0; i < 16; ++i)
      fresh &= (f[i][0] != NAN_S) & (f[i][4] != NAN_S);
    if (__all(fresh)) break;
    if (++guard > (1 << 13)) break;   // safety valve: degrade, never hang
  }
}

// ---------------------------------------------------------------------------
// prep: pack U mats into B-fragment order bf16; transpose W mats to [n][k]
// Upk[mat][c][kb][lane][j] = U[kb*32 + (lane>>4)*8 + j][c*16 + (lane&15)]
// ---------------------------------------------------------------------------
__global__ __launch_bounds__(256) void prep_kernel(
    const float* __restrict__ U0, const float* __restrict__ U1, const float* __restrict__ U2,
    const float* __restrict__ W0, const float* __restrict__ W1, const float* __restrict__ W2,
    short* __restrict__ Upk, short* __restrict__ Wt)
{
  int e = blockIdx.x * 256 + threadIdx.x;
  if (e < 786432) {
    int mat = e >> 18;
    int rem = e & 262143;
    int c   = rem >> 13;
    int r2  = rem & 8191;
    int kb  = r2 >> 9;
    int r3  = r2 & 511;
    int l = r3 >> 3, j = r3 & 7;
    int k = kb * 32 + ((l >> 4) << 3) + j;
    int d = c * 16 + (l & 15);
    const float* U = (mat == 0) ? U0 : (mat == 1 ? U1 : U2);
    Upk[e] = f2b(U[k * 512 + d]);
  } else if (e < 1572864) {
    int e2 = e - 786432;
    int mat = e2 >> 18;
    int rem = e2 & 262143;
    int n = rem >> 9, k = rem & 511;
    const float* W = (mat == 0) ? W0 : (mat == 1 ? W1 : W2);
    Wt[e2] = f2b(W[k * 512 + n]);
  }
}

// hb1 = h(-1) = zeros (valid); hb0/gb0/gb1 = sentinel; h_f32 = 0
__global__ __launch_bounds__(256) void init_kernel(
    short* hb0, short* hb1, short* gb0, short* gb1, float* h_f32)
{
  int e = blockIdx.x * 256 + threadIdx.x;
  if (e < 32768) {
    hb0[e] = NAN_S; hb1[e] = 0;
    gb0[e] = NAN_S; gb1[e] = NAN_S;
    h_f32[e] = 0.0f;
  }
}

// ---------------------------------------------------------------------------
// GEMM (per segment): out[mat][m][n] = bf16( X-row(base+m) . W[mat][:,n] + b )
// ---------------------------------------------------------------------------
__global__ __launch_bounds__(256) void gemm_xw(
    const float* __restrict__ X, const short* __restrict__ Wt,
    const float* __restrict__ bias0, const float* __restrict__ bias1,
    const float* __restrict__ bias2, short* __restrict__ out,
    int base_row, int cnt_rows)
{
  __shared__ __align__(16) short Al[128][48];
  __shared__ __align__(16) short Bl[128][48];
  const int bm = blockIdx.x, bn = blockIdx.y, mat = blockIdx.z;
  const short* Wm = Wt + (size_t)mat * (512 * 512);
  const float* bias = (mat == 0) ? bias0 : (mat == 1 ? bias1 : bias2);
  short* om = out + (size_t)mat * ((size_t)cnt_rows * 512);
  const int tid = threadIdx.x, lane = tid & 63, wid = tid >> 6;
  const int wm = wid >> 1, wn = wid & 1;
  const int m0 = bm * 128, n0g = bn * 128;
  f32x4 acc[4][4];
  #pragma unroll
  for (int i = 0; i < 4; ++i)
    #pragma unroll
    for (int j = 0; j < 4; ++j) acc[i][j] = (f32x4){0.f, 0.f, 0.f, 0.f};

  for (int k0 = 0; k0 < 512; k0 += 32) {
    #pragma unroll
    for (int i = 0; i < 4; ++i) {
      int q = tid + 256 * i;
      int r = q >> 3, seg = q & 7;
      int ml = m0 + r;
      short4v h4 = {0, 0, 0, 0};
      if (ml < cnt_rows) {
        int gl = base_row + ml;
        int t = gl >> 6, bb = gl & 63;
        floatx4 v = *(const floatx4*)(X + ((size_t)bb * 512 + t) * 512 + k0 + seg * 4);
        h4 = (short4v){ f2b(v[0]), f2b(v[1]), f2b(v[2]), f2b(v[3]) };
      }
      *(short4v*)&Al[r][seg * 4] = h4;
    }
    #pragma unroll
    for (int i = 0; i < 2; ++i) {
      int q = tid + 256 * i;
      int r = q >> 2, seg = q & 3;
      *(short8*)&Bl[r][seg * 8] = *(const short8*)(Wm + (size_t)(n0g + r) * 512 + k0 + seg * 8);
    }
    __syncthreads();
    const int ko = (lane >> 4) * 8;
    short8 af[4], bf4[4];
    #pragma unroll
    for (int mt = 0; mt < 4; ++mt)
      af[mt] = *(const short8*)&Al[wm * 64 + mt * 16 + (lane & 15)][ko];
    #pragma unroll
    for (int nt = 0; nt < 4; ++nt)
      bf4[nt] = *(const short8*)&Bl[wn * 64 + nt * 16 + (lane & 15)][ko];
    #pragma unroll
    for (int mt = 0; mt < 4; ++mt)
      #pragma unroll
      for (int nt = 0; nt < 4; ++nt)
        acc[mt][nt] = __builtin_amdgcn_mfma_f32_16x16x32_bf16(af[mt], bf4[nt], acc[mt][nt], 0, 0, 0);
    __syncthreads();
  }
  const int rq = lane >> 4, cq = lane & 15;
  #pragma unroll
  for (int mt = 0; mt < 4; ++mt) {
    #pragma unroll
    for (int nt = 0; nt < 4; ++nt) {
      int n = n0g + wn * 64 + nt * 16 + cq;
      float bv = bias[n];
      #pragma unroll
      for (int rr = 0; rr < 4; ++rr) {
        int m = m0 + wm * 64 + mt * 16 + rq * 4 + rr;
        if (m < cnt_rows) om[(size_t)m * 512 + n] = f2b(acc[mt][nt][rr] + bv);
      }
    }
  }
}

// ---------------------------------------------------------------------------
// scan segment: 128 blocks x 64 threads (1 wave). Domain g = blk>>5 owns
// batch rows [g*16, g*16+16); block c = blk&31 owns cols [c*16, c*16+16).
// Per-group h/g frag-major (8192 shorts): idx(row,k) = (k>>5)*512
//   + ((k>>3)&3)*128 + (row&15)*8 + (k&7). Group base = g*8192 shorts.
// Publish slice: 256 contiguous shorts at (c>>1)*512 + (c&1)*256.
// ---------------------------------------------------------------------------
__global__ __launch_bounds__(64, 1) void scan_kernel(
    short* hb0, short* hb1, short* gb0, short* gb1, float* h_f32,
    const short* __restrict__ Upk,
    const short* __restrict__ xx,
    const float* __restrict__ bu_in, const float* __restrict__ bu_out,
    float* __restrict__ out,
    int s0, int nsteps, int nt)
{
  __shared__ __align__(16) short Ub[3][16][64][8];   // 48 KB, B-frag-packed
  __shared__ __align__(16) short St[256];            // wave transpose stage
  const int lane = threadIdx.x & 63;
  const int g = blockIdx.x >> 5;          // batch domain
  const int c = blockIdx.x & 31;          // column owner
  {
    const size_t cs = (size_t)c * 8192;
    short8* dst = (short8*)Ub;
    for (int i = lane; i < 3072; i += 64) {
      int mat = i >> 10;
      int rem = i & 1023;
      dst[i] = *(const short8*)(Upk + (size_t)mat * 262144 + cs + (size_t)rem * 8);
    }
  }
  const int colg = c * 16 + (lane & 15);
  const float binr  = bu_in[colg];
  const float boutr = bu_out[colg];
  const size_t XSZ = (size_t)nt * 64 * 512;
  const int gbase = g * 8192;             // group sub-buffer (shorts)
  // consume base: lane's frag position within group buffer
  const int fofs = gbase + ((lane >> 4) << 7) + ((lane & 15) << 3);
  // publish base: block slice + lane*4
  const int pofs = gbase + ((c >> 1) << 9) + ((c & 1) << 8) + (lane << 2);
  // St transpose write index
  const int sw = ((lane & 15) >> 3) * 128 + ((lane >> 4) << 5) + (lane & 7);
  short* hbuf[2] = { hb0, hb1 };
  short* gbuf[2] = { gb0, gb1 };
  const int2v NANPAIR = { 0x7FFF7FFF, 0x7FFF7FFF };

  float hown[4];
  #pragma unroll
  for (int r = 0; r < 4; ++r)
    hown[r] = h_f32[(size_t)(g * 16 + (lane >> 4) * 4 + r) * 512 + colg];
  __syncthreads();

  for (int s = 0; s < nsteps; ++s) {
    const int sg = s0 + s;
    const int p = sg & 1;
    // hoisted xx loads for BOTH stages (cached) — overlap with poll
    float a1[4], a0[4], p1[4], p0[4], q1[4], q0[4];
    #pragma unroll
    for (int r = 0; r < 4; ++r) {
      int gr = g * 16 + (lane >> 4) * 4 + r;
      size_t i1 = ((size_t)(s + 1) * 64 + gr) * 512 + colg;
      size_t i0 = ((size_t)s * 64 + gr) * 512 + colg;
      a1[r] = b2f(xx[i1]);           a0[r] = b2f(xx[i0]);
      p1[r] = b2f(xx[XSZ + i1]);     p0[r] = b2f(xx[XSZ + i0]);
      q1[r] = b2f(xx[2 * XSZ + i1]); q0[r] = b2f(xx[2 * XSZ + i0]);
    }

    // ---- stage 1: poll h(sg-1); accin chain FIRST; publish g; then accu ----
    short8 afr[16];
    poll_frags16(hbuf[p ^ 1] + fofs, afr);
    // poll ok => all col-blocks of this group consumed g(sg-1) => reset slice
    if (sg > 0) st8_cp(gbuf[p ^ 1] + pofs, NANPAIR);

    f32x4 ai[4];
    ai[0] = ai[1] = ai[2] = ai[3] = (f32x4){0.f, 0.f, 0.f, 0.f};
    #pragma unroll
    for (int kb = 0; kb < 16; ++kb) {
      short8 b1 = *((const short8*)Ub + ((1 * 16 + kb) * 64 + lane));
      ai[kb & 3] = __builtin_amdgcn_mfma_f32_16x16x32_bf16(afr[kb], b1, ai[kb & 3], 0, 0, 0);
    }
    f32x4 accin = (ai[0] + ai[1]) + (ai[2] + ai[3]);
    #pragma unroll
    for (int r = 0; r < 4; ++r) {
      float zin = hsig(p1[r] + accin[r] + p0[r] + binr);
      St[sw + r * 8] = f2b(zin * hown[r]);
    }
    // publish g(sg) EARLY: wave-local LDS transpose -> one coalesced 8B store
    st8_cp(gbuf[p] + pofs, *(const int2v*)&St[lane << 2]);

    // accu chain overlaps g's flight
    f32x4 au[4];
    au[0] = au[1] = au[2] = au[3] = (f32x4){0.f, 0.f, 0.f, 0.f};
    #pragma unroll
    for (int kb = 0; kb < 16; ++kb) {
      short8 b0 = *((const short8*)Ub + ((0 * 16 + kb) * 64 + lane));
      au[kb & 3] = __builtin_amdgcn_mfma_f32_16x16x32_bf16(afr[kb], b0, au[kb & 3], 0, 0, 0);
    }
    f32x4 accu = (au[0] + au[1]) + (au[2] + au[3]);
    float zr[4];
    #pragma unroll
    for (int r = 0; r < 4; ++r)
      zr[r] = hsig(a1[r] + accu[r] + a0[r]);

    // ---- stage 2: poll g(sg), acco (4-way chains), publish h ----
    short8 gfr[16];
    poll_frags16(gbuf[p] + fofs, gfr);
    // poll ok => all consumed h(sg-1) => reset own hb[p^1] slice
    st8_cp(hbuf[p ^ 1] + pofs, NANPAIR);
    f32x4 ao[4];
    ao[0] = ao[1] = ao[2] = ao[3] = (f32x4){0.f, 0.f, 0.f, 0.f};
    #pragma unroll
    for (int kb = 0; kb < 16; ++kb) {
      short8 b2 = *((const short8*)Ub + ((2 * 16 + kb) * 64 + lane));
      ao[kb & 3] = __builtin_amdgcn_mfma_f32_16x16x32_bf16(gfr[kb], b2, ao[kb & 3], 0, 0, 0);
    }
    f32x4 acco = (ao[0] + ao[1]) + (ao[2] + ao[3]);
    #pragma unroll
    for (int r = 0; r < 4; ++r) {
      float pre = q1[r] + acco[r] + q0[r] + boutr;
      float zo = softplus_f(pre);
      float hn = (1.0f - zr[r]) * hown[r] + zr[r] * zo;
      hown[r] = hn;
      St[sw + r * 8] = f2b(hn);
    }
    // publish h(sg) EARLY (before the final-step out store)
    st8_cp(hbuf[p] + pofs, *(const int2v*)&St[lane << 2]);
    if (sg == NSTEP - 1) {
      #pragma unroll
      for (int r = 0; r < 4; ++r) {
        int gr = g * 16 + (lane >> 4) * 4 + r;
        out[(size_t)gr * 512 + colg] = hown[r];
      }
    }
  }
  // persist fp32 h for the next segment; drain publishes before exit
  #pragma unroll
  for (int r = 0; r < 4; ++r)
    h_f32[(size_t)(g * 16 + (lane >> 4) * 4 + r) * 512 + colg] = hown[r];
  asm volatile("s_waitcnt vmcnt(0)" ::: "memory");
}

extern "C" void kernel_launch(void* const* d_in, const int* in_sizes, int n_in,
                              void* d_out, int out_size, void* d_ws, size_t ws_size,
                              hipStream_t stream)
{
  const float* X      = (const float*)d_in[0];
  const float* W      = (const float*)d_in[1];
  const float* b      = (const float*)d_in[2];
  const float* W_in   = (const float*)d_in[3];
  const float* b_in   = (const float*)d_in[4];
  const float* W_out  = (const float*)d_in[5];
  const float* b_out  = (const float*)d_in[6];
  const float* U      = (const float*)d_in[7];
  const float* U_in   = (const float*)d_in[8];
  const float* U_out  = (const float*)d_in[9];
  const float* bu_in  = (const float*)d_in[10];
  const float* bu_out = (const float*)d_in[11];
  float* out = (float*)d_out;
  char* ws = (char*)d_ws;
  short* hb0  = (short*)(ws + OFF_HB0);
  short* hb1  = (short*)(ws + OFF_HB1);
  short* gb0  = (short*)(ws + OFF_GB0);
  short* gb1  = (short*)(ws + OFF_GB1);
  float* h_f32= (float*)(ws + OFF_HF32);
  short* Upk  = (short*)(ws + OFF_UPK);
  short* Wt   = (short*)(ws + OFF_WT);
  short* xx   = (short*)(ws + OFF_XX);

  size_t avail = (ws_size > (size_t)OFF_XX) ? ws_size - (size_t)OFF_XX : 0;
  int max_t = (int)(avail / PER_T_BYTES);
  if (max_t > 512) max_t = 512;
  int SEG = max_t - 1;
  if (SEG < 1) SEG = 1;

  prep_kernel<<<6144, 256, 0, stream>>>(U, U_in, U_out, W, W_in, W_out, Upk, Wt);
  init_kernel<<<128, 256, 0, stream>>>(hb0, hb1, gb0, gb1, h_f32);

  int s0 = 0;
  while (s0 < NSTEP) {
    int nsteps = NSTEP - s0; if (nsteps > SEG) nsteps = SEG;
    int nt = nsteps + 1;
    int rows = nt * 64;
    int gx = (rows + 127) / 128;
    gemm_xw<<<dim3(gx, 4, 3), 256, 0, stream>>>(X, Wt, b, b_in, b_out, xx,
                                                s0 * 64, rows);
    scan_kernel<<<NGRP * NCOLB, 64, 0, stream>>>(hb0, hb1, gb0, gb1, h_f32,
                                                 Upk, xx, bu_in, bu_out, out,
                                                 s0, nsteps, nt);
    s0 += nsteps;
  }
}